// Round 9
// baseline (168.055 us; speedup 1.0000x reference)
//
#include <hip/hip_runtime.h>
#include <math.h>

#define EDIM   1024
#define KVEDIM 256
#define HDIM   64
#define QHEADS 16

typedef __attribute__((ext_vector_type(8))) short short8;   // 8 bf16 (4 VGPRs)
typedef __attribute__((ext_vector_type(4))) float f32x4;

// fp32 -> bf16 (RNE)
__device__ __forceinline__ short f2b(float a) {
    unsigned ua = __builtin_bit_cast(unsigned, a);
    ua += 0x7fffu + ((ua >> 16) & 1u);
    return (short)(ua >> 16);
}
// packed RNE f32->bf16 pair in one instruction
__device__ __forceinline__ unsigned cvtpk(float a, float b) {
    unsigned r;
    asm("v_cvt_pk_bf16_f32 %0, %1, %2" : "=v"(r) : "v"(a), "v"(b));
    return r;
}

// ---------------------------------------------------------------------------
// Fused-convert projection GEMM with REGISTER-PREFETCH pipeline (r8 fix):
// the fp32 global loads for k-step t+1 are issued right after the barrier of
// step t and consumed at step t+1's LDS-write -- load latency hides under the
// MFMA compute instead of sitting between the two barriers (attn's proven
// structure). C[M,N] = (A[M,K] @ W[N,K]^T + bias) * scale.
// 64x64 tile, BK=64, 256 threads (4 waves, each 32x32 via 2x2 MFMA tiles).
// Grid decode: [0,512) = q, [512,640) = k, [640,768) = v.
// V output stored TRANSPOSED ([d][token], row stride n).
// ---------------------------------------------------------------------------
__global__ __launch_bounds__(256)
void proj_gemm(const float* __restrict__ Aq, const float* __restrict__ Ak,
               const float* __restrict__ Av,
               const float* __restrict__ Wqf, const float* __restrict__ Wkf,
               const float* __restrict__ Wvf,
               const float* __restrict__ bq, const float* __restrict__ bk,
               const float* __restrict__ bv,
               short* __restrict__ Cq, short* __restrict__ Ck,
               short* __restrict__ Cv, float qscale, int n)
{
    const int bid = blockIdx.x;
    const float* A; const float* W; const float* bias; short* C;
    int N, bm, bn; float scale; int vtrans;
    if (bid < 512) {
        A = Aq; W = Wqf; bias = bq; C = Cq; N = EDIM; scale = qscale; vtrans = 0;
        bm = (bid >> 4) * 64; bn = (bid & 15) * 64;
    } else if (bid < 640) {
        int i = bid - 512;
        A = Ak; W = Wkf; bias = bk; C = Ck; N = KVEDIM; scale = 1.0f; vtrans = 0;
        bm = (i >> 2) * 64; bn = (i & 3) * 64;
    } else {
        int i = bid - 640;
        A = Av; W = Wvf; bias = bv; C = Cv; N = KVEDIM; scale = 1.0f; vtrans = 1;
        bm = (i >> 2) * 64; bn = (i & 3) * 64;
    }
    const int K = EDIM;

    __shared__ short As[64 * 72];
    __shared__ short Ws[64 * 72];

    const int t = threadIdx.x, lane = t & 63, wv = t >> 6;
    const int lm = lane & 15, quad = lane >> 4;
    const int q8 = quad * 8, q4 = quad * 4;
    const int wm = (wv & 1) * 32, wn = (wv >> 1) * 32;
    const int sr = t >> 2, c0 = (t & 3) * 16;   // staging: row, 16-float col base

    const f32x4 zero = {0.f, 0.f, 0.f, 0.f};
    f32x4 acc[2][2] = {{zero, zero}, {zero, zero}};

    const float* arow = &A[(size_t)(bm + sr) * K + c0];
    const float* wrow = &W[(size_t)(bn + sr) * K + c0];

    // prologue: prefetch k0 = 0 panel into registers
    float4 a0, a1, a2, a3, w0, w1, w2, w3;
    {
        const float4* ap = (const float4*)arow;
        a0 = ap[0]; a1 = ap[1]; a2 = ap[2]; a3 = ap[3];
        const float4* wp = (const float4*)wrow;
        w0 = wp[0]; w1 = wp[1]; w2 = wp[2]; w3 = wp[3];
    }

    for (int k0 = 0; k0 < K; k0 += 64) {
        // ---- convert staged registers and write LDS ----
        {
            uint4 o0, o1;
            o0.x = cvtpk(a0.x, a0.y); o0.y = cvtpk(a0.z, a0.w);
            o0.z = cvtpk(a1.x, a1.y); o0.w = cvtpk(a1.z, a1.w);
            o1.x = cvtpk(a2.x, a2.y); o1.y = cvtpk(a2.z, a2.w);
            o1.z = cvtpk(a3.x, a3.y); o1.w = cvtpk(a3.z, a3.w);
            *(uint4*)&As[sr * 72 + c0]     = o0;
            *(uint4*)&As[sr * 72 + c0 + 8] = o1;
            uint4 p0, p1;
            p0.x = cvtpk(w0.x, w0.y); p0.y = cvtpk(w0.z, w0.w);
            p0.z = cvtpk(w1.x, w1.y); p0.w = cvtpk(w1.z, w1.w);
            p1.x = cvtpk(w2.x, w2.y); p1.y = cvtpk(w2.z, w2.w);
            p1.z = cvtpk(w3.x, w3.y); p1.w = cvtpk(w3.z, w3.w);
            *(uint4*)&Ws[sr * 72 + c0]     = p0;
            *(uint4*)&Ws[sr * 72 + c0 + 8] = p1;
        }
        __syncthreads();

        // ---- issue next k-step's global loads (consumed next iteration) ----
        if (k0 + 64 < K) {
            const float4* ap = (const float4*)&arow[k0 + 64];
            a0 = ap[0]; a1 = ap[1]; a2 = ap[2]; a3 = ap[3];
            const float4* wp = (const float4*)&wrow[k0 + 64];
            w0 = wp[0]; w1 = wp[1]; w2 = wp[2]; w3 = wp[3];
        }

        // ---- compute ----
        #pragma unroll
        for (int ks = 0; ks < 2; ++ks) {
            short8 af[2], bfr[2];
            #pragma unroll
            for (int i = 0; i < 2; ++i)
                af[i] = *(const short8*)&As[(wm + i * 16 + lm) * 72 + ks * 32 + q8];
            #pragma unroll
            for (int j = 0; j < 2; ++j)
                bfr[j] = *(const short8*)&Ws[(wn + j * 16 + lm) * 72 + ks * 32 + q8];
            #pragma unroll
            for (int i = 0; i < 2; ++i)
                #pragma unroll
                for (int j = 0; j < 2; ++j)
                    acc[i][j] = __builtin_amdgcn_mfma_f32_16x16x32_bf16(
                        af[i], bfr[j], acc[i][j], 0, 0, 0);
        }
        __syncthreads();   // readers done before next iteration's LDS writes
    }

    if (!vtrans) {
        #pragma unroll
        for (int j = 0; j < 2; ++j) {
            float bj = bias[bn + wn + j * 16 + lm];
            #pragma unroll
            for (int i = 0; i < 2; ++i)
                #pragma unroll
                for (int r = 0; r < 4; ++r)
                    C[(size_t)(bm + wm + i * 16 + q4 + r) * N + bn + wn + j * 16 + lm] =
                        f2b((acc[i][j][r] + bj) * scale);
        }
    } else {
        // transposed store: row = d (bn+wn+j*16+lm), cols = 4 consecutive tokens
        #pragma unroll
        for (int j = 0; j < 2; ++j) {
            float bj = bias[bn + wn + j * 16 + lm];
            const size_t drow = (size_t)(bn + wn + j * 16 + lm) * n;
            #pragma unroll
            for (int i = 0; i < 2; ++i) {
                uint2 o;
                o.x = cvtpk(acc[i][j][0] + bj, acc[i][j][1] + bj);
                o.y = cvtpk(acc[i][j][2] + bj, acc[i][j][3] + bj);
                *(uint2*)&C[drow + bm + wm + i * 16 + q4] = o;
            }
        }
    }
}

// ---------------------------------------------------------------------------
// MFMA flash attention, QBLK=32 (r8 structure, unchanged math). Partials are
// now written in BF16 (halves the opart WRITE + ln READ traffic; P is already
// bf16 in the PV MFMA so relative error stays ~0.4%, far under threshold).
// Block = 32 q-rows x 4 q-heads (one wave per q-head), one shared KV head;
// blockIdx.z = KV split. Grid 64x4x4 = 1024 blocks.
// K staging/reads and V slot layout: r3/r7-exact (measured 0 conflicts).
// ---------------------------------------------------------------------------
__global__ __launch_bounds__(256, 4)
void attn_mfma(const short* __restrict__ q, const short* __restrict__ k,
               const short* __restrict__ vt, float* __restrict__ x,
               short* __restrict__ opart, float* __restrict__ lpart,
               int n, int s_len, int partial)
{
    __shared__ short Ks[64 * 64];   // K chunk [token][d], swizzled (8 KB)
    __shared__ short Vs[4096];      // V chunk, r3 slot layout     (8 KB)

    const int kvh = blockIdx.y;
    const int r0  = blockIdx.x * 32;
    const int t = threadIdx.x, lane = t & 63, wv = t >> 6;
    const int qh = (kvh << 2) | wv;          // wave's q-head
    const int lm = lane & 15, quad = lane >> 4, q8 = quad * 8;

    // Q B-fragments for this wave's TWO 16-row q-tiles (reused every chunk)
    short8 qf[2][2];
    #pragma unroll
    for (int qt = 0; qt < 2; ++qt) {
        const short* qp = &q[(size_t)(r0 + qt * 16 + lm) * EDIM + qh * HDIM];
        qf[qt][0] = *(const short8*)&qp[q8];
        qf[qt][1] = *(const short8*)&qp[32 + q8];
    }

    const f32x4 zero = {0.f, 0.f, 0.f, 0.f};
    f32x4 oacc[2][4];               // [qt][dt], O[qrow=quad*4+r][d=dt*16+lm]
    #pragma unroll
    for (int qt = 0; qt < 2; ++qt)
        #pragma unroll
        for (int dt = 0; dt < 4; ++dt) oacc[qt][dt] = zero;
    float lp[2] = {0.f, 0.f};

    // K staging map (r3-exact)
    const int sr  = t >> 2;                  // K token row (0..63)
    const int scs = (t & 3) * 16;            // col base (shorts)
    const int swS = (sr & 7) << 3;
    const int kw0 = sr * 64 + (scs ^ swS);
    const int kw1 = sr * 64 + ((scs + 8) ^ swS);
    // K read column offsets (swizzled)
    const int krx  = q8 ^ ((lm & 7) << 3);
    const int krx2 = (32 + q8) ^ ((lm & 7) << 3);

    // V staging map: thread owns V^T row vd, token quarter vc
    const int vd = t >> 2, vc = t & 3;
    const int vktp = vc >> 1, vhalf = vc & 1;
    int vsx[4];
    #pragma unroll
    for (int p = 0; p < 4; ++p) {
        int slot = ((vd >> 4) << 7) + (vktp << 6) + (p << 4) + (vd & 15);
        vsx[p] = slot ^ ((slot >> 4) & 7);
    }

    const int s_lo = (int)blockIdx.z * s_len;
    const int nt = s_len >> 6;
    const short* kb = k + (size_t)kvh * HDIM;                    // K rows
    const short* vb = vt + (size_t)(kvh * HDIM + vd) * n;        // this V^T row

    // prefetch first chunk into registers
    uint4 kra, krb, vra, vrb;
    {
        const uint4* ks = (const uint4*)&kb[(size_t)(s_lo + sr) * KVEDIM + scs];
        kra = ks[0]; krb = ks[1];
        const uint4* vs = (const uint4*)&vb[s_lo + vc * 16];
        vra = vs[0]; vrb = vs[1];
    }

    for (int it = 0; it < nt; ++it) {
        // ---- write staged registers to LDS ----
        *(uint4*)&Ks[kw0] = kra;
        *(uint4*)&Ks[kw1] = krb;
        {
            uint2 o;
            o.x = vra.x; o.y = vra.y; *(uint2*)&Vs[vsx[0] * 8 + vhalf * 4] = o;
            o.x = vra.z; o.y = vra.w; *(uint2*)&Vs[vsx[1] * 8 + vhalf * 4] = o;
            o.x = vrb.x; o.y = vrb.y; *(uint2*)&Vs[vsx[2] * 8 + vhalf * 4] = o;
            o.x = vrb.z; o.y = vrb.w; *(uint2*)&Vs[vsx[3] * 8 + vhalf * 4] = o;
        }
        __syncthreads();

        // ---- issue next chunk's global loads early (hide under compute) ----
        if (it + 1 < nt) {
            const int s1 = s_lo + (it + 1) * 64;
            const uint4* ks = (const uint4*)&kb[(size_t)(s1 + sr) * KVEDIM + scs];
            kra = ks[0]; krb = ks[1];
            const uint4* vs = (const uint4*)&vb[s1 + vc * 16];
            vra = vs[0]; vrb = vs[1];
        }

        // ---- S' = K . Q^T for both q-tiles; K frags read ONCE per kt ----
        uint2 pa[2][4];
        #pragma unroll
        for (int kt = 0; kt < 4; ++kt) {
            const int krow = (kt * 16 + lm) * 64;
            short8 kf0 = *(const short8*)&Ks[krow + krx];
            short8 kf1 = *(const short8*)&Ks[krow + krx2];
            #pragma unroll
            for (int qt = 0; qt < 2; ++qt) {
                f32x4 s = zero;
                s = __builtin_amdgcn_mfma_f32_16x16x32_bf16(kf0, qf[qt][0], s, 0, 0, 0);
                s = __builtin_amdgcn_mfma_f32_16x16x32_bf16(kf1, qf[qt][1], s, 0, 0, 0);
                float p0 = exp2f(s[0]), p1 = exp2f(s[1]);
                float p2 = exp2f(s[2]), p3 = exp2f(s[3]);
                lp[qt] += (p0 + p1) + (p2 + p3);
                pa[qt][kt].x = cvtpk(p0, p1);    // keys kt*16+quad*4+{0,1}
                pa[qt][kt].y = cvtpk(p2, p3);    // keys kt*16+quad*4+{2,3}
            }
        }

        // ---- O += P . V : V frags read ONCE per dt, used by both q-tiles ----
        uint4 ap[2][2];
        #pragma unroll
        for (int qt = 0; qt < 2; ++qt) {
            ap[qt][0].x = pa[qt][0].x; ap[qt][0].y = pa[qt][0].y;
            ap[qt][0].z = pa[qt][1].x; ap[qt][0].w = pa[qt][1].y;
            ap[qt][1].x = pa[qt][2].x; ap[qt][1].y = pa[qt][2].y;
            ap[qt][1].z = pa[qt][3].x; ap[qt][1].w = pa[qt][3].y;
        }
        #pragma unroll
        for (int dt = 0; dt < 4; ++dt) {
            int sb0 = dt * 128 + quad * 16 + lm;          // ktp=0
            int sx0 = sb0 ^ ((sb0 >> 4) & 7);
            int sb1 = sb0 + 64;                           // ktp=1
            int sx1 = sb1 ^ ((sb1 >> 4) & 7);
            short8 vf0 = *(const short8*)&Vs[sx0 * 8];
            short8 vf1 = *(const short8*)&Vs[sx1 * 8];
            #pragma unroll
            for (int qt = 0; qt < 2; ++qt) {
                oacc[qt][dt] = __builtin_amdgcn_mfma_f32_16x16x32_bf16(
                    __builtin_bit_cast(short8, ap[qt][0]), vf0, oacc[qt][dt], 0, 0, 0);
                oacc[qt][dt] = __builtin_amdgcn_mfma_f32_16x16x32_bf16(
                    __builtin_bit_cast(short8, ap[qt][1]), vf1, oacc[qt][dt], 0, 0, 0);
            }
        }
        __syncthreads();
    }

    // ---- epilogue per q-tile ----
    #pragma unroll
    for (int qt = 0; qt < 2; ++qt) {
        float lt = lp[qt];
        lt += __shfl_xor(lt, 16);
        lt += __shfl_xor(lt, 32);
        // every lane holds the full l-sum for qrow = lm (of tile qt)

        if (partial) {
            short* xp = opart + (size_t)blockIdx.z * n * EDIM;
            if (lane < 16)
                lpart[(size_t)blockIdx.z * n * QHEADS +
                      (size_t)(r0 + qt * 16 + lane) * QHEADS + qh] = lt;
            #pragma unroll
            for (int r = 0; r < 4; ++r) {
                const int row = r0 + qt * 16 + quad * 4 + r;
                #pragma unroll
                for (int dt = 0; dt < 4; ++dt)
                    xp[(size_t)row * EDIM + qh * HDIM + dt * 16 + lm] =
                        f2b(oacc[qt][dt][r]);
            }
        } else {
            float linv[4];
            #pragma unroll
            for (int r = 0; r < 4; ++r)
                linv[r] = 1.0f / __shfl(lt, quad * 4 + r);
            #pragma unroll
            for (int r = 0; r < 4; ++r) {
                const int row = r0 + qt * 16 + quad * 4 + r;
                #pragma unroll
                for (int dt = 0; dt < 4; ++dt)
                    x[(size_t)row * EDIM + qh * HDIM + dt * 16 + lm] =
                        oacc[qt][dt][r] * linv[r];
            }
        }
    }
}

// ---------------------------------------------------------------------------
// Split-KV combine (bf16 unnormalized O partials / fp32 l partials) + LN.
// nsplit == 0: plain in-place LN on x (fallback path).
// ---------------------------------------------------------------------------
__global__ __launch_bounds__(256)
void ln_kernel(float* __restrict__ x, const float* __restrict__ gamma,
               const float* __restrict__ beta,
               const short* __restrict__ opart, const float* __restrict__ lpart,
               int nsplit, int n)
{
    const int row = blockIdx.x;
    const int t = threadIdx.x;

    float4 xv;
    if (nsplit > 0) {
        const int head = t >> 4;                 // (t*4)/64
        float l = 0.f;
        float4 s = {0.f, 0.f, 0.f, 0.f};
        for (int z = 0; z < nsplit; ++z) {
            const uint2 raw = *(const uint2*)&opart[(size_t)z * n * EDIM +
                                                    (size_t)row * EDIM + t * 4];
            s.x += __builtin_bit_cast(float, raw.x << 16);
            s.y += __builtin_bit_cast(float, raw.x & 0xffff0000u);
            s.z += __builtin_bit_cast(float, raw.y << 16);
            s.w += __builtin_bit_cast(float, raw.y & 0xffff0000u);
            l += lpart[(size_t)z * n * QHEADS + (size_t)row * QHEADS + head];
        }
        const float inv = 1.f / l;
        xv.x = s.x * inv; xv.y = s.y * inv; xv.z = s.z * inv; xv.w = s.w * inv;
    } else {
        xv = *(const float4*)&x[(size_t)row * EDIM + t * 4];
    }

    float sm  = xv.x + xv.y + xv.z + xv.w;
    float sq = xv.x * xv.x + xv.y * xv.y + xv.z * xv.z + xv.w * xv.w;
    #pragma unroll
    for (int m = 1; m < 64; m <<= 1) {
        sm += __shfl_xor(sm, m);
        sq += __shfl_xor(sq, m);
    }
    __shared__ float ws_[4], wq_[4];
    const int wave = t >> 6;
    if ((t & 63) == 0) { ws_[wave] = sm; wq_[wave] = sq; }
    __syncthreads();
    sm = ws_[0] + ws_[1] + ws_[2] + ws_[3];
    sq = wq_[0] + wq_[1] + wq_[2] + wq_[3];

    const float mu   = sm * (1.f / EDIM);
    const float var  = sq * (1.f / EDIM) - mu * mu;
    const float rstd = rsqrtf(var + 1e-5f);

    float4 g = *(const float4*)&gamma[t * 4];
    float4 b = *(const float4*)&beta[t * 4];
    float4 o;
    o.x = (xv.x - mu) * rstd * g.x + b.x;
    o.y = (xv.y - mu) * rstd * g.y + b.y;
    o.z = (xv.z - mu) * rstd * g.z + b.z;
    o.w = (xv.w - mu) * rstd * g.w + b.w;
    *(float4*)&x[(size_t)row * EDIM + t * 4] = o;
}

// ---------------------------------------------------------------------------
extern "C" void kernel_launch(void* const* d_in, const int* in_sizes, int n_in,
                              void* d_out, int out_size, void* d_ws, size_t ws_size,
                              hipStream_t stream)
{
    const float* query = (const float*)d_in[0];
    const float* key   = (const float*)d_in[1];
    const float* value = (const float*)d_in[2];
    const float* Wq    = (const float*)d_in[3];
    const float* bq    = (const float*)d_in[4];
    const float* Wk    = (const float*)d_in[5];
    const float* bk    = (const float*)d_in[6];
    const float* Wv    = (const float*)d_in[7];
    const float* bv    = (const float*)d_in[8];
    const float* gamma = (const float*)d_in[9];
    const float* beta  = (const float*)d_in[10];
    float* out = (float*)d_out;

    const int n = in_sizes[0] / EDIM;   // 2048

    // workspace layout: projection outputs (bf16), bf16 O-partials, fp32 l
    short* qb  = (short*)d_ws;                 // q proj      n*1024
    short* kb  = qb + (size_t)n * EDIM;        // k proj      n*256
    short* vtb = kb + (size_t)n * KVEDIM;      // v proj, TRANSPOSED 256*n
    short* ws_end = vtb + (size_t)KVEDIM * n;

    const size_t base_bytes = (size_t)((char*)ws_end - (char*)d_ws);
    int nsplit = 0;
    for (int cand = 4; cand >= 1; cand >>= 1) {
        if (n % (64 * cand)) continue;
        size_t need = base_bytes +
                      (size_t)cand * ((size_t)n * EDIM * sizeof(short) +
                                      (size_t)n * QHEADS * sizeof(float));
        if (need <= ws_size) { nsplit = cand; break; }
    }
    short* opart = ws_end;                                    // bf16 partials
    float* lpart = (float*)(opart +
                   (size_t)(nsplit > 0 ? nsplit : 1) * n * EDIM);

    // 1/sqrt(64) * log2(e): exp2-based softmax without max subtraction
    const float qscale = 0.125f * 1.44269504088896f;

    proj_gemm<<<dim3(768), 256, 0, stream>>>(
        query, key, value, Wq, Wk, Wv, bq, bk, bv, qb, kb, vtb, qscale, n);

    const int zdim  = (nsplit > 0) ? nsplit : 1;
    const int s_len = n / zdim;
    attn_mfma<<<dim3(n / 32, 4, zdim), 256, 0, stream>>>(
        qb, kb, vtb, out, opart, lpart, n, s_len, nsplit > 0 ? 1 : 0);

    ln_kernel<<<dim3(n), 256, 0, stream>>>(out, gamma, beta, opart, lpart, nsplit, n);
}

// Round 10
// 150.889 us; speedup vs baseline: 1.1138x; 1.1138x over previous
//
#include <hip/hip_runtime.h>
#include <math.h>

#define EDIM   1024
#define KVEDIM 256
#define HDIM   64
#define QHEADS 16

typedef __attribute__((ext_vector_type(8))) short short8;   // 8 bf16 (4 VGPRs)
typedef __attribute__((ext_vector_type(4))) float f32x4;

// fp32 -> bf16 (RNE)
__device__ __forceinline__ short f2b(float a) {
    unsigned ua = __builtin_bit_cast(unsigned, a);
    ua += 0x7fffu + ((ua >> 16) & 1u);
    return (short)(ua >> 16);
}
// packed RNE f32->bf16 pair in one instruction
__device__ __forceinline__ unsigned cvtpk(float a, float b) {
    unsigned r;
    asm("v_cvt_pk_bf16_f32 %0, %1, %2" : "=v"(r) : "v"(a), "v"(b));
    return r;
}

// ---------------------------------------------------------------------------
// Fused-convert projection GEMM: C[M,N] = (A[M,K] @ W[N,K]^T + bias) * scale,
// A and W read as fp32 and converted to bf16 in-register during staging.
// 64x64 tile, BK=64, 256 threads (4 waves, each 32x32 via 2x2 MFMA tiles).
// Grid decode: [0,512) = q, [512,640) = k, [640,768) = v.
// V output stored TRANSPOSED ([d][token], row stride n).
// (r9's register-prefetch variant REVERTED: +32 VGPRs of fp32 panel in
// flight regressed total by ~8 us; this plain version measured best, r8.)
// ---------------------------------------------------------------------------
__global__ __launch_bounds__(256)
void proj_gemm(const float* __restrict__ Aq, const float* __restrict__ Ak,
               const float* __restrict__ Av,
               const float* __restrict__ Wqf, const float* __restrict__ Wkf,
               const float* __restrict__ Wvf,
               const float* __restrict__ bq, const float* __restrict__ bk,
               const float* __restrict__ bv,
               short* __restrict__ Cq, short* __restrict__ Ck,
               short* __restrict__ Cv, float qscale, int n)
{
    const int bid = blockIdx.x;
    const float* A; const float* W; const float* bias; short* C;
    int N, bm, bn; float scale; int vtrans;
    if (bid < 512) {
        A = Aq; W = Wqf; bias = bq; C = Cq; N = EDIM; scale = qscale; vtrans = 0;
        bm = (bid >> 4) * 64; bn = (bid & 15) * 64;
    } else if (bid < 640) {
        int i = bid - 512;
        A = Ak; W = Wkf; bias = bk; C = Ck; N = KVEDIM; scale = 1.0f; vtrans = 0;
        bm = (i >> 2) * 64; bn = (i & 3) * 64;
    } else {
        int i = bid - 640;
        A = Av; W = Wvf; bias = bv; C = Cv; N = KVEDIM; scale = 1.0f; vtrans = 1;
        bm = (i >> 2) * 64; bn = (i & 3) * 64;
    }
    const int K = EDIM;

    __shared__ short As[64 * 72];
    __shared__ short Ws[64 * 72];

    const int t = threadIdx.x, lane = t & 63, wv = t >> 6;
    const int lm = lane & 15, quad = lane >> 4;
    const int q8 = quad * 8, q4 = quad * 4;
    const int wm = (wv & 1) * 32, wn = (wv >> 1) * 32;
    const int sr = t >> 2, c0 = (t & 3) * 16;   // staging: row, 16-float col base

    const f32x4 zero = {0.f, 0.f, 0.f, 0.f};
    f32x4 acc[2][2] = {{zero, zero}, {zero, zero}};

    for (int k0 = 0; k0 < K; k0 += 64) {
        __syncthreads();
        {
            const float4* ap = (const float4*)&A[(size_t)(bm + sr) * K + k0 + c0];
            float4 a0 = ap[0], a1 = ap[1], a2 = ap[2], a3 = ap[3];
            uint4 o0, o1;
            o0.x = cvtpk(a0.x, a0.y); o0.y = cvtpk(a0.z, a0.w);
            o0.z = cvtpk(a1.x, a1.y); o0.w = cvtpk(a1.z, a1.w);
            o1.x = cvtpk(a2.x, a2.y); o1.y = cvtpk(a2.z, a2.w);
            o1.z = cvtpk(a3.x, a3.y); o1.w = cvtpk(a3.z, a3.w);
            *(uint4*)&As[sr * 72 + c0]     = o0;
            *(uint4*)&As[sr * 72 + c0 + 8] = o1;
            const float4* wp = (const float4*)&W[(size_t)(bn + sr) * K + k0 + c0];
            float4 w0 = wp[0], w1 = wp[1], w2 = wp[2], w3 = wp[3];
            uint4 p0, p1;
            p0.x = cvtpk(w0.x, w0.y); p0.y = cvtpk(w0.z, w0.w);
            p0.z = cvtpk(w1.x, w1.y); p0.w = cvtpk(w1.z, w1.w);
            p1.x = cvtpk(w2.x, w2.y); p1.y = cvtpk(w2.z, w2.w);
            p1.z = cvtpk(w3.x, w3.y); p1.w = cvtpk(w3.z, w3.w);
            *(uint4*)&Ws[sr * 72 + c0]     = p0;
            *(uint4*)&Ws[sr * 72 + c0 + 8] = p1;
        }
        __syncthreads();
        #pragma unroll
        for (int ks = 0; ks < 2; ++ks) {
            short8 af[2], bfr[2];
            #pragma unroll
            for (int i = 0; i < 2; ++i)
                af[i] = *(const short8*)&As[(wm + i * 16 + lm) * 72 + ks * 32 + q8];
            #pragma unroll
            for (int j = 0; j < 2; ++j)
                bfr[j] = *(const short8*)&Ws[(wn + j * 16 + lm) * 72 + ks * 32 + q8];
            #pragma unroll
            for (int i = 0; i < 2; ++i)
                #pragma unroll
                for (int j = 0; j < 2; ++j)
                    acc[i][j] = __builtin_amdgcn_mfma_f32_16x16x32_bf16(
                        af[i], bfr[j], acc[i][j], 0, 0, 0);
        }
    }

    if (!vtrans) {
        #pragma unroll
        for (int j = 0; j < 2; ++j) {
            float bj = bias[bn + wn + j * 16 + lm];
            #pragma unroll
            for (int i = 0; i < 2; ++i)
                #pragma unroll
                for (int r = 0; r < 4; ++r)
                    C[(size_t)(bm + wm + i * 16 + q4 + r) * N + bn + wn + j * 16 + lm] =
                        f2b((acc[i][j][r] + bj) * scale);
        }
    } else {
        // transposed store: row = d (bn+wn+j*16+lm), cols = 4 consecutive tokens
        #pragma unroll
        for (int j = 0; j < 2; ++j) {
            float bj = bias[bn + wn + j * 16 + lm];
            const size_t drow = (size_t)(bn + wn + j * 16 + lm) * n;
            #pragma unroll
            for (int i = 0; i < 2; ++i) {
                uint2 o;
                o.x = cvtpk(acc[i][j][0] + bj, acc[i][j][1] + bj);
                o.y = cvtpk(acc[i][j][2] + bj, acc[i][j][3] + bj);
                *(uint2*)&C[drow + bm + wm + i * 16 + q4] = o;
            }
        }
    }
}

// ---------------------------------------------------------------------------
// MFMA flash attention, QBLK=32: each wave handles TWO 16-row q-tiles of its
// head, reusing every staged K/V byte and every ds_read across both tiles.
// Block = 32 q-rows x 4 q-heads (one wave per q-head), one shared KV head;
// blockIdx.z = KV split (associative no-max exp2 softmax -> unnormalized
// FP32 partials combined in ln_kernel; r9's bf16 partials REVERTED -- the
// scalar-short epilogue perturbed codegen into a spill: VGPR 64, +25 MB
// scratch traffic, attn 41 -> 46.5 us).
// Grid 64x4x4 = 1024 blocks. launch_bounds(256,4): cap 128, no spill.
// K staging/reads and V slot layout: r3/r7-exact (measured 0 conflicts).
// QK^T operand-swapped; PV packs two 16-key tiles into one full-K=32 MFMA,
// element-matched to the V slot content (r3-verified pairing).
// ---------------------------------------------------------------------------
__global__ __launch_bounds__(256, 4)
void attn_mfma(const short* __restrict__ q, const short* __restrict__ k,
               const short* __restrict__ vt, float* __restrict__ x,
               float* __restrict__ opart, float* __restrict__ lpart,
               int n, int s_len, int partial)
{
    __shared__ short Ks[64 * 64];   // K chunk [token][d], swizzled (8 KB)
    __shared__ short Vs[4096];      // V chunk, r3 slot layout     (8 KB)

    const int kvh = blockIdx.y;
    const int r0  = blockIdx.x * 32;
    const int t = threadIdx.x, lane = t & 63, wv = t >> 6;
    const int qh = (kvh << 2) | wv;          // wave's q-head
    const int lm = lane & 15, quad = lane >> 4, q8 = quad * 8;

    // Q B-fragments for this wave's TWO 16-row q-tiles (reused every chunk)
    short8 qf[2][2];
    #pragma unroll
    for (int qt = 0; qt < 2; ++qt) {
        const short* qp = &q[(size_t)(r0 + qt * 16 + lm) * EDIM + qh * HDIM];
        qf[qt][0] = *(const short8*)&qp[q8];
        qf[qt][1] = *(const short8*)&qp[32 + q8];
    }

    const f32x4 zero = {0.f, 0.f, 0.f, 0.f};
    f32x4 oacc[2][4];               // [qt][dt], O[qrow=quad*4+r][d=dt*16+lm]
    #pragma unroll
    for (int qt = 0; qt < 2; ++qt)
        #pragma unroll
        for (int dt = 0; dt < 4; ++dt) oacc[qt][dt] = zero;
    float lp[2] = {0.f, 0.f};

    // K staging map (r3-exact)
    const int sr  = t >> 2;                  // K token row (0..63)
    const int scs = (t & 3) * 16;            // col base (shorts)
    const int swS = (sr & 7) << 3;
    const int kw0 = sr * 64 + (scs ^ swS);
    const int kw1 = sr * 64 + ((scs + 8) ^ swS);
    // K read column offsets (swizzled)
    const int krx  = q8 ^ ((lm & 7) << 3);
    const int krx2 = (32 + q8) ^ ((lm & 7) << 3);

    // V staging map: thread owns V^T row vd, token quarter vc
    const int vd = t >> 2, vc = t & 3;
    const int vktp = vc >> 1, vhalf = vc & 1;
    int vsx[4];
    #pragma unroll
    for (int p = 0; p < 4; ++p) {
        int slot = ((vd >> 4) << 7) + (vktp << 6) + (p << 4) + (vd & 15);
        vsx[p] = slot ^ ((slot >> 4) & 7);
    }

    const int s_lo = (int)blockIdx.z * s_len;
    const int nt = s_len >> 6;
    const short* kb = k + (size_t)kvh * HDIM;                    // K rows
    const short* vb = vt + (size_t)(kvh * HDIM + vd) * n;        // this V^T row

    // prefetch first chunk into registers
    uint4 kra, krb, vra, vrb;
    {
        const uint4* ks = (const uint4*)&kb[(size_t)(s_lo + sr) * KVEDIM + scs];
        kra = ks[0]; krb = ks[1];
        const uint4* vs = (const uint4*)&vb[s_lo + vc * 16];
        vra = vs[0]; vrb = vs[1];
    }

    for (int it = 0; it < nt; ++it) {
        // ---- write staged registers to LDS ----
        *(uint4*)&Ks[kw0] = kra;
        *(uint4*)&Ks[kw1] = krb;
        {
            uint2 o;
            o.x = vra.x; o.y = vra.y; *(uint2*)&Vs[vsx[0] * 8 + vhalf * 4] = o;
            o.x = vra.z; o.y = vra.w; *(uint2*)&Vs[vsx[1] * 8 + vhalf * 4] = o;
            o.x = vrb.x; o.y = vrb.y; *(uint2*)&Vs[vsx[2] * 8 + vhalf * 4] = o;
            o.x = vrb.z; o.y = vrb.w; *(uint2*)&Vs[vsx[3] * 8 + vhalf * 4] = o;
        }
        __syncthreads();

        // ---- issue next chunk's global loads early (hide under compute) ----
        if (it + 1 < nt) {
            const int s1 = s_lo + (it + 1) * 64;
            const uint4* ks = (const uint4*)&kb[(size_t)(s1 + sr) * KVEDIM + scs];
            kra = ks[0]; krb = ks[1];
            const uint4* vs = (const uint4*)&vb[s1 + vc * 16];
            vra = vs[0]; vrb = vs[1];
        }

        // ---- S' = K . Q^T for both q-tiles; K frags read ONCE per kt ----
        uint2 pa[2][4];
        #pragma unroll
        for (int kt = 0; kt < 4; ++kt) {
            const int krow = (kt * 16 + lm) * 64;
            short8 kf0 = *(const short8*)&Ks[krow + krx];
            short8 kf1 = *(const short8*)&Ks[krow + krx2];
            #pragma unroll
            for (int qt = 0; qt < 2; ++qt) {
                f32x4 s = zero;
                s = __builtin_amdgcn_mfma_f32_16x16x32_bf16(kf0, qf[qt][0], s, 0, 0, 0);
                s = __builtin_amdgcn_mfma_f32_16x16x32_bf16(kf1, qf[qt][1], s, 0, 0, 0);
                float p0 = exp2f(s[0]), p1 = exp2f(s[1]);
                float p2 = exp2f(s[2]), p3 = exp2f(s[3]);
                lp[qt] += (p0 + p1) + (p2 + p3);
                pa[qt][kt].x = cvtpk(p0, p1);    // keys kt*16+quad*4+{0,1}
                pa[qt][kt].y = cvtpk(p2, p3);    // keys kt*16+quad*4+{2,3}
            }
        }

        // ---- O += P . V : V frags read ONCE per dt, used by both q-tiles ----
        uint4 ap[2][2];
        #pragma unroll
        for (int qt = 0; qt < 2; ++qt) {
            ap[qt][0].x = pa[qt][0].x; ap[qt][0].y = pa[qt][0].y;
            ap[qt][0].z = pa[qt][1].x; ap[qt][0].w = pa[qt][1].y;
            ap[qt][1].x = pa[qt][2].x; ap[qt][1].y = pa[qt][2].y;
            ap[qt][1].z = pa[qt][3].x; ap[qt][1].w = pa[qt][3].y;
        }
        #pragma unroll
        for (int dt = 0; dt < 4; ++dt) {
            int sb0 = dt * 128 + quad * 16 + lm;          // ktp=0
            int sx0 = sb0 ^ ((sb0 >> 4) & 7);
            int sb1 = sb0 + 64;                           // ktp=1
            int sx1 = sb1 ^ ((sb1 >> 4) & 7);
            short8 vf0 = *(const short8*)&Vs[sx0 * 8];
            short8 vf1 = *(const short8*)&Vs[sx1 * 8];
            #pragma unroll
            for (int qt = 0; qt < 2; ++qt) {
                oacc[qt][dt] = __builtin_amdgcn_mfma_f32_16x16x32_bf16(
                    __builtin_bit_cast(short8, ap[qt][0]), vf0, oacc[qt][dt], 0, 0, 0);
                oacc[qt][dt] = __builtin_amdgcn_mfma_f32_16x16x32_bf16(
                    __builtin_bit_cast(short8, ap[qt][1]), vf1, oacc[qt][dt], 0, 0, 0);
            }
        }
        __syncthreads();
    }

    // ---- epilogue per q-tile ----
    #pragma unroll
    for (int qt = 0; qt < 2; ++qt) {
        float lt = lp[qt];
        lt += __shfl_xor(lt, 16);
        lt += __shfl_xor(lt, 32);
        // every lane holds the full l-sum for qrow = lm (of tile qt)

        if (partial) {
            float* xp = opart + (size_t)blockIdx.z * n * EDIM;
            if (lane < 16)
                lpart[(size_t)blockIdx.z * n * QHEADS +
                      (size_t)(r0 + qt * 16 + lane) * QHEADS + qh] = lt;
            #pragma unroll
            for (int r = 0; r < 4; ++r) {
                const int row = r0 + qt * 16 + quad * 4 + r;
                #pragma unroll
                for (int dt = 0; dt < 4; ++dt)
                    xp[(size_t)row * EDIM + qh * HDIM + dt * 16 + lm] = oacc[qt][dt][r];
            }
        } else {
            float linv[4];
            #pragma unroll
            for (int r = 0; r < 4; ++r)
                linv[r] = 1.0f / __shfl(lt, quad * 4 + r);
            #pragma unroll
            for (int r = 0; r < 4; ++r) {
                const int row = r0 + qt * 16 + quad * 4 + r;
                #pragma unroll
                for (int dt = 0; dt < 4; ++dt)
                    x[(size_t)row * EDIM + qh * HDIM + dt * 16 + lm] =
                        oacc[qt][dt][r] * linv[r];
            }
        }
    }
}

// ---------------------------------------------------------------------------
// Split-KV combine (fp32 unnormalized O partials / l partials) + LayerNorm.
// nsplit == 0: plain in-place LN on x (fallback path).
// ---------------------------------------------------------------------------
__global__ __launch_bounds__(256)
void ln_kernel(float* __restrict__ x, const float* __restrict__ gamma,
               const float* __restrict__ beta,
               const float* __restrict__ opart, const float* __restrict__ lpart,
               int nsplit, int n)
{
    const int row = blockIdx.x;
    const int t = threadIdx.x;

    float4 xv;
    if (nsplit > 0) {
        const int head = t >> 4;                 // (t*4)/64
        float l = 0.f;
        float4 s = {0.f, 0.f, 0.f, 0.f};
        for (int z = 0; z < nsplit; ++z) {
            const float4 o = *(const float4*)&opart[(size_t)z * n * EDIM +
                                                    (size_t)row * EDIM + t * 4];
            s.x += o.x; s.y += o.y; s.z += o.z; s.w += o.w;
            l += lpart[(size_t)z * n * QHEADS + (size_t)row * QHEADS + head];
        }
        const float inv = 1.f / l;
        xv.x = s.x * inv; xv.y = s.y * inv; xv.z = s.z * inv; xv.w = s.w * inv;
    } else {
        xv = *(const float4*)&x[(size_t)row * EDIM + t * 4];
    }

    float sm  = xv.x + xv.y + xv.z + xv.w;
    float sq = xv.x * xv.x + xv.y * xv.y + xv.z * xv.z + xv.w * xv.w;
    #pragma unroll
    for (int m = 1; m < 64; m <<= 1) {
        sm += __shfl_xor(sm, m);
        sq += __shfl_xor(sq, m);
    }
    __shared__ float ws_[4], wq_[4];
    const int wave = t >> 6;
    if ((t & 63) == 0) { ws_[wave] = sm; wq_[wave] = sq; }
    __syncthreads();
    sm = ws_[0] + ws_[1] + ws_[2] + ws_[3];
    sq = wq_[0] + wq_[1] + wq_[2] + wq_[3];

    const float mu   = sm * (1.f / EDIM);
    const float var  = sq * (1.f / EDIM) - mu * mu;
    const float rstd = rsqrtf(var + 1e-5f);

    float4 g = *(const float4*)&gamma[t * 4];
    float4 b = *(const float4*)&beta[t * 4];
    float4 o;
    o.x = (xv.x - mu) * rstd * g.x + b.x;
    o.y = (xv.y - mu) * rstd * g.y + b.y;
    o.z = (xv.z - mu) * rstd * g.z + b.z;
    o.w = (xv.w - mu) * rstd * g.w + b.w;
    *(float4*)&x[(size_t)row * EDIM + t * 4] = o;
}

// ---------------------------------------------------------------------------
extern "C" void kernel_launch(void* const* d_in, const int* in_sizes, int n_in,
                              void* d_out, int out_size, void* d_ws, size_t ws_size,
                              hipStream_t stream)
{
    const float* query = (const float*)d_in[0];
    const float* key   = (const float*)d_in[1];
    const float* value = (const float*)d_in[2];
    const float* Wq    = (const float*)d_in[3];
    const float* bq    = (const float*)d_in[4];
    const float* Wk    = (const float*)d_in[5];
    const float* bk    = (const float*)d_in[6];
    const float* Wv    = (const float*)d_in[7];
    const float* bv    = (const float*)d_in[8];
    const float* gamma = (const float*)d_in[9];
    const float* beta  = (const float*)d_in[10];
    float* out = (float*)d_out;

    const int n = in_sizes[0] / EDIM;   // 2048

    // workspace layout: projection outputs (bf16), then fp32 split partials
    short* qb  = (short*)d_ws;                 // q proj      n*1024
    short* kb  = qb + (size_t)n * EDIM;        // k proj      n*256
    short* vtb = kb + (size_t)n * KVEDIM;      // v proj, TRANSPOSED 256*n
    short* ws_end = vtb + (size_t)KVEDIM * n;

    const size_t base_bytes = (size_t)((char*)ws_end - (char*)d_ws);
    int nsplit = 0;
    for (int cand = 4; cand >= 1; cand >>= 1) {
        if (n % (64 * cand)) continue;
        size_t need = base_bytes +
                      (size_t)cand * ((size_t)n * EDIM + (size_t)n * QHEADS) * sizeof(float);
        if (need <= ws_size) { nsplit = cand; break; }
    }
    float* opart = (float*)ws_end;
    float* lpart = opart + (size_t)(nsplit > 0 ? nsplit : 1) * n * EDIM;

    // 1/sqrt(64) * log2(e): exp2-based softmax without max subtraction
    const float qscale = 0.125f * 1.44269504088896f;

    proj_gemm<<<dim3(768), 256, 0, stream>>>(
        query, key, value, Wq, Wk, Wv, bq, bk, bv, qb, kb, vtb, qscale, n);

    const int zdim  = (nsplit > 0) ? nsplit : 1;
    const int s_len = n / zdim;
    attn_mfma<<<dim3(n / 32, 4, zdim), 256, 0, stream>>>(
        qb, kb, vtb, out, opart, lpart, n, s_len, nsplit > 0 ? 1 : 0);

    ln_kernel<<<dim3(n), 256, 0, stream>>>(out, gamma, beta, opart, lpart, nsplit, n);
}